// Round 1
// baseline (3228.813 us; speedup 1.0000x reference)
//
#include <hip/hip_runtime.h>

#define L 512
#define OD 508
#define KER 5
#define KTOP 100
#define NBINS 4096
#define CAP 4096

// ---------------- r computation (shared by hist + collect) ----------------
// r[b,i,j] = (x*S - T) * count, where
//   S = sum of w[p][q] over valid taps, T = sum of kern_avg over covering
//   windows, kern_avg[m] = (out[m] - bias)/25  (out holds conv(x,w)+bias).
__device__ __forceinline__ float compute_r(const float* __restrict__ x,
                                           const float* __restrict__ out,
                                           const float* wsm, float bias,
                                           int b, int i, int j) {
    int p_lo = max(0, i - (OD - 1));
    int p_hi = min(KER - 1, i);
    int q_lo = max(0, j - (OD - 1));
    int q_hi = min(KER - 1, j);
    float S = 0.f, Tsum = 0.f;
    const float* outb = out + (size_t)b * OD * OD;
    for (int p = p_lo; p <= p_hi; ++p) {
        int mh = i - p;
        for (int q = q_lo; q <= q_hi; ++q) {
            S += wsm[p * KER + q];
            Tsum += outb[mh * OD + (j - q)];
        }
    }
    int n = (p_hi - p_lo + 1) * (q_hi - q_lo + 1);
    float T = (Tsum - (float)n * bias) * (1.0f / 25.0f);
    float xv = x[((size_t)b * L + i) * L + j];
    return (xv * S - T) * (float)n;
}

// ---------------- 1. conv(x,w)+bias -> d_out ----------------
__global__ void conv_kernel(const float* __restrict__ x,
                            const float* __restrict__ w,
                            const float* __restrict__ bias,
                            float* __restrict__ out) {
    __shared__ float wsm[25];
    int lin = threadIdx.y * blockDim.x + threadIdx.x;
    if (lin < 25) wsm[lin] = w[lin];
    __syncthreads();
    int b = blockIdx.z;
    int i = blockIdx.y * 16 + threadIdx.y;
    int j = blockIdx.x * 16 + threadIdx.x;
    if (i >= OD || j >= OD) return;
    const float* xb = x + (size_t)b * L * L;
    float acc = 0.f;
#pragma unroll
    for (int p = 0; p < KER; ++p)
#pragma unroll
        for (int q = 0; q < KER; ++q)
            acc += xb[(i + p) * L + (j + q)] * wsm[p * KER + q];
    out[((size_t)b * OD + i) * OD + j] = acc + bias[0];
}

// ---------------- 2. per-batch histogram of key = bits(|r|) ----------------
__global__ void hist_kernel(const float* __restrict__ x,
                            const float* __restrict__ out,
                            const float* __restrict__ w,
                            const float* __restrict__ bias,
                            unsigned int* __restrict__ hist) {
    __shared__ float wsm[25];
    __shared__ unsigned int lh[NBINS];
    int tid = threadIdx.x;
    if (tid < 25) wsm[tid] = w[tid];
    for (int t = tid; t < NBINS; t += blockDim.x) lh[t] = 0;
    __syncthreads();
    int b = blockIdx.y;
    float bv = bias[0];
    int pix_per_block = (L * L) / gridDim.x;
    int start = blockIdx.x * pix_per_block;
    for (int t = tid; t < pix_per_block; t += blockDim.x) {
        int idx = start + t;
        int i = idx >> 9, j = idx & (L - 1);
        float r = compute_r(x, out, wsm, bv, b, i, j);
        unsigned int key = __float_as_uint(fabsf(r));
        atomicAdd(&lh[key >> 19], 1u);
    }
    __syncthreads();
    unsigned int* gh = hist + (size_t)b * NBINS;
    for (int t = tid; t < NBINS; t += blockDim.x)
        if (lh[t]) atomicAdd(&gh[t], lh[t]);
}

// ---------------- 3. find candidate-bin lower bound per batch ----------------
__global__ void scan_kernel(const unsigned int* __restrict__ hist,
                            unsigned int* __restrict__ lo_key) {
    int b = blockIdx.x * blockDim.x + threadIdx.x;
    if (b >= 256) return;
    const unsigned int* h = hist + (size_t)b * NBINS;
    unsigned int cum = 0;
    int bin = NBINS - 1;
    for (; bin >= 0; --bin) {
        cum += h[bin];
        if (cum >= KTOP) break;
    }
    if (bin < 0) bin = 0;
    lo_key[b] = ((unsigned int)bin) << 19;
}

// ---------------- 4. collect candidates (key >= lo) ----------------
__global__ void collect_kernel(const float* __restrict__ x,
                               const float* __restrict__ out,
                               const float* __restrict__ w,
                               const float* __restrict__ bias,
                               const unsigned int* __restrict__ lo_key,
                               unsigned int* __restrict__ cnt,
                               unsigned long long* __restrict__ cand) {
    __shared__ float wsm[25];
    if (threadIdx.x < 25) wsm[threadIdx.x] = w[threadIdx.x];
    __syncthreads();
    int b = blockIdx.y;
    unsigned int lo = lo_key[b];
    float bv = bias[0];
    int pix_per_block = (L * L) / gridDim.x;
    int start = blockIdx.x * pix_per_block;
    unsigned long long* cb = cand + (size_t)b * CAP;
    for (int t = threadIdx.x; t < pix_per_block; t += blockDim.x) {
        int idx = start + t;
        int i = idx >> 9, j = idx & (L - 1);
        float r = compute_r(x, out, wsm, bv, b, i, j);
        unsigned int key = __float_as_uint(fabsf(r));
        if (key >= lo) {
            unsigned int pos = atomicAdd(&cnt[b], 1u);
            if (pos < CAP)
                cb[pos] = ((unsigned long long)key << 32) |
                          (unsigned int)(~(unsigned int)idx);
        }
    }
}

// ---------------- 5. sort candidates, take top-100, subtract taps ----------------
__global__ void select_apply_kernel(const float* __restrict__ x,
                                    const float* __restrict__ w,
                                    const unsigned int* __restrict__ cnt,
                                    const unsigned long long* __restrict__ cand,
                                    float* __restrict__ out) {
    __shared__ unsigned long long buf[CAP];
    __shared__ float wsm[25];
    int tid = threadIdx.x;
    int b = blockIdx.x;
    if (tid < 25) wsm[tid] = w[tid];
    unsigned int n = min(cnt[b], (unsigned int)CAP);
    const unsigned long long* cb = cand + (size_t)b * CAP;
    for (int t = tid; t < CAP; t += blockDim.x)
        buf[t] = (t < (int)n) ? cb[t] : 0ULL;
    __syncthreads();
    // bitonic sort, descending by (key, ~idx) => key desc, idx asc on ties
    for (int k = 2; k <= CAP; k <<= 1) {
        for (int j = k >> 1; j > 0; j >>= 1) {
            for (int t = tid; t < CAP; t += blockDim.x) {
                int ixj = t ^ j;
                if (ixj > t) {
                    unsigned long long a = buf[t], c = buf[ixj];
                    bool desc = ((t & k) == 0);
                    if (desc ? (a < c) : (a > c)) {
                        buf[t] = c;
                        buf[ixj] = a;
                    }
                }
            }
            __syncthreads();
        }
    }
    int nsel = min((unsigned int)KTOP, n);
    const float* xb = x + (size_t)b * L * L;
    float* outb = out + (size_t)b * OD * OD;
    for (int t = tid; t < nsel * 25; t += blockDim.x) {
        int s = t / 25, tap = t % 25;
        unsigned int idx = ~(unsigned int)(buf[s] & 0xFFFFFFFFu);
        int u = (int)(idx >> 9), v = (int)(idx & (L - 1));
        int p = tap / 5, q = tap % 5;
        int mh = u - p, mw = v - q;
        if (mh >= 0 && mh < OD && mw >= 0 && mw < OD) {
            float delta = xb[(size_t)u * L + v] * wsm[tap];
            atomicAdd(&outb[(size_t)mh * OD + mw], -delta);
        }
    }
}

extern "C" void kernel_launch(void* const* d_in, const int* in_sizes, int n_in,
                              void* d_out, int out_size, void* d_ws, size_t ws_size,
                              hipStream_t stream) {
    const float* x = (const float*)d_in[0];
    const float* w = (const float*)d_in[1];
    const float* bias = (const float*)d_in[2];
    float* out = (float*)d_out;
    int B = in_sizes[0] / (L * L); // 256

    char* ws = (char*)d_ws;
    const size_t hist_bytes = (size_t)256 * NBINS * sizeof(unsigned int); // 4 MB
    unsigned int* hist = (unsigned int*)ws;
    unsigned int* cnt = (unsigned int*)(ws + hist_bytes);          // 1 KB
    unsigned int* lo = (unsigned int*)(ws + hist_bytes + 1024);    // 1 KB
    unsigned long long* cand = (unsigned long long*)(ws + hist_bytes + 2048);

    // zero hist + cnt (ws is poisoned 0xAA before every launch)
    hipMemsetAsync(hist, 0, hist_bytes + 1024, stream);

    conv_kernel<<<dim3((OD + 15) / 16, (OD + 15) / 16, B), dim3(16, 16), 0, stream>>>(
        x, w, bias, out);
    hist_kernel<<<dim3(32, B), 256, 0, stream>>>(x, out, w, bias, hist);
    scan_kernel<<<1, 256, 0, stream>>>(hist, lo);
    collect_kernel<<<dim3(32, B), 256, 0, stream>>>(x, out, w, bias, lo, cnt, cand);
    select_apply_kernel<<<B, 256, 0, stream>>>(x, w, cnt, cand, out);
}